// Round 5
// baseline (502.638 us; speedup 1.0000x reference)
//
#include <hip/hip_runtime.h>

typedef unsigned short ushort_t;
typedef __attribute__((ext_vector_type(8))) short short8;
typedef __attribute__((ext_vector_type(4))) float floatx4;

#define B_ 8
#define S_ 4096
#define E_ 1024
#define SD_ 8
#define M_TOTAL (B_ * S_)   /* 32768 rows */
#define NC 1032             /* E+SD real columns of W_in */
#define NCH 256             /* scan chunks */
#define CHS (S_ / NCH)      /* 16 steps per chunk */

__device__ __forceinline__ ushort_t f2bf(float f) {
    union { float f; unsigned u; } v; v.f = f;
    unsigned u = v.u;
    unsigned r = (u + 0x7fffu + ((u >> 16) & 1u)) >> 16;  // RNE
    return (ushort_t)r;
}
__device__ __forceinline__ float bf2f(ushort_t h) {
    union { unsigned u; float f; } v; v.u = ((unsigned)h) << 16;
    return v.f;
}

// Async global->LDS, 16B per lane. LDS dest is wave-uniform base + lane*16.
__device__ __forceinline__ void stage16(ushort_t* lds_base_uniform, const ushort_t* g) {
    __builtin_amdgcn_global_load_lds(
        (const __attribute__((address_space(1))) void*)g,
        (__attribute__((address_space(3))) void*)lds_base_uniform, 16, 0, 0);
}

// ---------------- prepass kernels (R1-proven chain, unchanged) ----------------

// Wc[1024][8] = W_in[1024][1032] @ W_g[1032][8]  (fp32, one wave per row)
__global__ void wcomb_kernel(const float* __restrict__ W_in, const float* __restrict__ Wg,
                             float* __restrict__ Wc) {
    const int k = blockIdx.x;          // row 0..1023
    const int lane = threadIdx.x;      // 64
    float acc[8] = {0.f,0.f,0.f,0.f,0.f,0.f,0.f,0.f};
    for (int c = lane; c < NC; c += 64) {
        float w = W_in[(size_t)k * NC + c];
#pragma unroll
        for (int d = 0; d < 8; d++) acc[d] += w * Wg[(size_t)c * 8 + d];
    }
#pragma unroll
    for (int d = 0; d < 8; d++) {
#pragma unroll
        for (int off = 32; off >= 1; off >>= 1) acc[d] += __shfl_xor(acc[d], off);
    }
    if (lane == 0) {
#pragma unroll
        for (int d = 0; d < 8; d++) Wc[k * 8 + d] = acc[d];
    }
}

// Winb[1024][1024] bf16 = W_in[:, :1024] (coalesced, float4 in / ushort4 out)
__global__ void prep_winb(const float* __restrict__ W, ushort_t* __restrict__ O) {
    int i = blockIdx.x * 256 + threadIdx.x;    // over 1024 * 256
    int k = i >> 8, j0 = (i & 255) * 4;
    float4 v = *(const float4*)(W + (size_t)k * NC + j0);
    ushort4 o;
    o.x = f2bf(v.x); o.y = f2bf(v.y); o.z = f2bf(v.z); o.w = f2bf(v.w);
    *(ushort4*)(O + (size_t)k * E_ + j0) = o;
}

// WoutTa[1024][1024] bf16: WoutTa[n][j] = W_out[j][n]  (j < 1024 only)
__global__ void prep_wouts(const float* __restrict__ W, ushort_t* __restrict__ O) {
    int idx = blockIdx.x * 256 + threadIdx.x;  // 1024*1024
    int n = idx >> 10, j = idx & 1023;
    O[idx] = f2bf(W[(size_t)j * E_ + n]);
}

// BT16[32][1024]: rows 0..7 = W_in[:,1024+n]^T, 8..15 = Wc[:,n-8]^T, 16..31 = 0
// WoutT2[1024][32]: [n][k2] = W_out[1024+k2][n] for k2<8 else 0
// bias16[32]: [0..7]=b_in[1024+d]; [8..15]=b_g[d]+b_in@W_g[:,d]; rest 0
__global__ void prep_small(const float* __restrict__ W_in, const float* __restrict__ Wc,
                           const float* __restrict__ W_out, const float* __restrict__ b_in,
                           const float* __restrict__ Wg, const float* __restrict__ bg,
                           ushort_t* __restrict__ BT16, ushort_t* __restrict__ WoutT2,
                           float* __restrict__ bias16) {
    int idx = blockIdx.x * 256 + threadIdx.x;  // 65536 total
    if (idx < 32768) {
        int n = idx >> 10, k = idx & 1023;
        float v;
        if (n < 8)        v = W_in[(size_t)k * NC + 1024 + n];
        else if (n < 16)  v = Wc[k * 8 + (n - 8)];
        else              v = 0.f;
        BT16[idx] = f2bf(v);
    } else {
        int i2 = idx - 32768;
        int n = i2 >> 5, k2 = i2 & 31;
        float v = (k2 < 8) ? W_out[(size_t)(1024 + k2) * E_ + n] : 0.f;
        WoutT2[i2] = f2bf(v);
    }
    if (idx < 32) {
        float s;
        if (idx < 8) s = b_in[1024 + idx];
        else if (idx < 16) {
            int d = idx - 8;
            s = bg[d];
            for (int j = 0; j < NC; j++) s += b_in[j] * Wg[(size_t)j * 8 + d];
        } else s = 0.f;
        bias16[idx] = s;
    }
}

// bias2[n] = b_out[n] + sum_{j<1024} b_in[j] * W_out[j][n]
__global__ void bias2_kernel(const float* __restrict__ b_in, const float* __restrict__ W_out,
                             const float* __restrict__ b_out, float* __restrict__ bias2) {
    int n = blockIdx.x * 64 + threadIdx.x;     // grid 16 x 64
    float acc = b_out[n];
    for (int j = 0; j < E_; j++) acc += b_in[j] * W_out[(size_t)j * E_ + n];
    bias2[n] = acc;
}

// ---------------- m97-style bf16 MFMA GEMM, B-transposed (R1-proven) ----------------
// C[M][N] = A[M][K] * BT[N][K]^T (+ optional extra 32-wide K-step from A2/BT2) + bias.
template <bool OUT_BF16, bool EXTRA>
__global__ __launch_bounds__(256, 2) void gemm_bt(
    const ushort_t* __restrict__ A, const ushort_t* __restrict__ BT,
    const ushort_t* __restrict__ A2, const ushort_t* __restrict__ BT2,
    void* __restrict__ Cout, const float* __restrict__ bias,
    int K, int lda, int ldb, int lda2, int ldb2, int ldc)
{
    __shared__ __align__(16) ushort_t sA[128 * 32];
    __shared__ __align__(16) ushort_t sB[128 * 32];
    const int tid = threadIdx.x;
    const int wave = tid >> 6;
    const int lane = tid & 63;

    const int gx = gridDim.x;
    int flat = blockIdx.y * gx + blockIdx.x;     // HW dispatch order (x fastest)
    const int band_size = 8 * gx;                // 8 panels per band
    int band = flat / band_size;
    int r = flat - band * band_size;
    const int m0 = (band * 8 + (r & 7)) * 128;   // panel: constant per-XCD within a band
    const int n0 = (r >> 3) * 128;

    const int wm = wave >> 1, wn = wave & 1;   // 2x2 waves -> 64x64 each
    const int fr = lane & 15, fq = lane >> 4;  // fragment row / k-quad
    const int sr = lane >> 2;                  // staging row-in-16
    const int sc = (lane & 3) * 8;             // staging k-chunk (elems)

    floatx4 acc[4][4];
#pragma unroll
    for (int i = 0; i < 4; i++)
#pragma unroll
        for (int j = 0; j < 4; j++) acc[i][j] = (floatx4)0.f;

    const ushort_t* gA = A + (size_t)(m0 + wave * 32 + sr) * lda + sc;
    const ushort_t* gB = BT + (size_t)(n0 + wave * 32 + sr) * ldb + sc;

    for (int k0 = 0; k0 < K; k0 += 32) {
        __syncthreads();
        stage16(&sA[(wave * 32 + 0) * 32], gA + k0);
        stage16(&sA[(wave * 32 + 16) * 32], gA + (size_t)16 * lda + k0);
        stage16(&sB[(wave * 32 + 0) * 32], gB + k0);
        stage16(&sB[(wave * 32 + 16) * 32], gB + (size_t)16 * ldb + k0);
        __syncthreads();  // drains vmcnt(0) for global_load_lds

        short8 a[4], b[4];
#pragma unroll
        for (int i = 0; i < 4; i++)
            a[i] = *(const short8*)&sA[(wm * 64 + i * 16 + fr) * 32 + fq * 8];
#pragma unroll
        for (int j = 0; j < 4; j++)
            b[j] = *(const short8*)&sB[(wn * 64 + j * 16 + fr) * 32 + fq * 8];
#pragma unroll
        for (int i = 0; i < 4; i++)
#pragma unroll
            for (int j = 0; j < 4; j++)
                acc[i][j] = __builtin_amdgcn_mfma_f32_16x16x32_bf16(a[i], b[j], acc[i][j], 0, 0, 0);
    }

    if constexpr (EXTRA) {
        // one more 32-wide K-step from the (A2, BT2) pair (states @ W_out2)
        const ushort_t* gA2 = A2 + (size_t)(m0 + wave * 32 + sr) * lda2 + sc;
        const ushort_t* gB2 = BT2 + (size_t)(n0 + wave * 32 + sr) * ldb2 + sc;
        __syncthreads();
        stage16(&sA[(wave * 32 + 0) * 32], gA2);
        stage16(&sA[(wave * 32 + 16) * 32], gA2 + (size_t)16 * lda2);
        stage16(&sB[(wave * 32 + 0) * 32], gB2);
        stage16(&sB[(wave * 32 + 16) * 32], gB2 + (size_t)16 * ldb2);
        __syncthreads();

        short8 a[4], b[4];
#pragma unroll
        for (int i = 0; i < 4; i++)
            a[i] = *(const short8*)&sA[(wm * 64 + i * 16 + fr) * 32 + fq * 8];
#pragma unroll
        for (int j = 0; j < 4; j++)
            b[j] = *(const short8*)&sB[(wn * 64 + j * 16 + fr) * 32 + fq * 8];
#pragma unroll
        for (int i = 0; i < 4; i++)
#pragma unroll
            for (int j = 0; j < 4; j++)
                acc[i][j] = __builtin_amdgcn_mfma_f32_16x16x32_bf16(a[i], b[j], acc[i][j], 0, 0, 0);
    }

    // epilogue: C/D layout col=lane&15, row=(lane>>4)*4+reg   [m89-verified]
#pragma unroll
    for (int i = 0; i < 4; i++) {
        int row = m0 + wm * 64 + i * 16 + fq * 4;
#pragma unroll
        for (int j = 0; j < 4; j++) {
            int col = n0 + wn * 64 + j * 16 + fr;
            float bv = bias ? bias[col] : 0.f;
#pragma unroll
            for (int r2 = 0; r2 < 4; r2++) {
                float v = acc[i][j][r2] + bv;
                if (OUT_BF16)
                    ((ushort_t*)Cout)[(size_t)(row + r2) * ldc + col] = f2bf(v);
                else
                    ((float*)Cout)[(size_t)(row + r2) * ldc + col] = v;
            }
        }
    }
}

// ---------------- fused cvt + skinny GEMM1 (the ONE new element this round) ------
// Reads x fp32 once: writes xb (bf16) as a side effect, computes
// comb16[32768][32] = bf16(x) @ BT16^T + bias16 (cols 0..7 state_in, 8..15 gate, 16..31 pad0)
__global__ __launch_bounds__(256) void skinny16_cvt(
    const float* __restrict__ X,        // x [32768][1024] fp32
    const ushort_t* __restrict__ BT,    // BT16 [32][1024] (rows 16..31 zero)
    const float* __restrict__ bias,     // [32]
    ushort_t* __restrict__ xb,          // out: bf16 copy of x
    ushort_t* __restrict__ C)           // comb16 [32768][32]
{
    const int tid = threadIdx.x, wave = tid >> 6, lane = tid & 63;
    const int m0 = blockIdx.x * 64 + wave * 16;   // 16 rows per wave
    const int fr = lane & 15, fq = lane >> 4;
    floatx4 acc0 = (floatx4)0.f;
    const float*    px  = X  + (size_t)(m0 + fr) * E_ + fq * 8;
    ushort_t*       pxb = xb + (size_t)(m0 + fr) * E_ + fq * 8;
    const ushort_t* pb0 = BT + (size_t)fr * E_ + fq * 8;   // B rows 0..15 (16..31 zero)
    for (int k0 = 0; k0 < E_; k0 += 32) {
        float4 v0 = *(const float4*)(px + k0);
        float4 v1 = *(const float4*)(px + k0 + 4);
        short8 a;
        a[0] = (short)f2bf(v0.x); a[1] = (short)f2bf(v0.y);
        a[2] = (short)f2bf(v0.z); a[3] = (short)f2bf(v0.w);
        a[4] = (short)f2bf(v1.x); a[5] = (short)f2bf(v1.y);
        a[6] = (short)f2bf(v1.z); a[7] = (short)f2bf(v1.w);
        *(short8*)(pxb + k0) = a;                           // 16B store
        short8 b0 = *(const short8*)(pb0 + k0);
        acc0 = __builtin_amdgcn_mfma_f32_16x16x32_bf16(a, b0, acc0, 0, 0, 0);
    }
#pragma unroll
    for (int r = 0; r < 4; r++) {
        int row = m0 + fq * 4 + r;
        C[(size_t)row * 32 + fr]      = f2bf(acc0[r] + bias[fr]);
        C[(size_t)row * 32 + 16 + fr] = (ushort_t)0;   // zero pad cols 16..31
    }
}

// ---------------- scan: state = g*state + (1-g)*si, chunked 2-pass ----------------
__global__ void scan_chunks(const ushort_t* __restrict__ comb,
                            float* __restrict__ chA, float* __restrict__ chB)
{
    const int c = blockIdx.x, lane = threadIdx.x;
    const int b = lane >> 3, d = lane & 7;
    float A = 1.f, Bv = 0.f;
    const int s0 = c * CHS;
    for (int s = s0; s < s0 + CHS; s++) {
        size_t m = (size_t)b * S_ + s;
        float z = bf2f(comb[m * 32 + 8 + d]);
        float g = 1.f / (1.f + __expf(-z));
        float si = bf2f(comb[m * 32 + d]);
        Bv = g * Bv + (1.f - g) * si;
        A *= g;
    }
    chA[c * 64 + lane] = A;
    chB[c * 64 + lane] = Bv;
}

__global__ void scan_apply(ushort_t* __restrict__ comb,
                           const float* __restrict__ chA, const float* __restrict__ chB,
                           float* __restrict__ final_state)
{
    const int c = blockIdx.x, lane = threadIdx.x;
    const int b = lane >> 3, d = lane & 7;
    float state = 0.f;  // state0 = 0
    for (int j = 0; j < c; j++)
        state = chA[j * 64 + lane] * state + chB[j * 64 + lane];
    const int s0 = c * CHS;
    for (int s = s0; s < s0 + CHS; s++) {
        size_t m = (size_t)b * S_ + s;
        float z = bf2f(comb[m * 32 + 8 + d]);
        float g = 1.f / (1.f + __expf(-z));
        float si = bf2f(comb[m * 32 + d]);
        state = g * state + (1.f - g) * si;
        comb[m * 32 + d] = f2bf(state);  // overwrite si with state for GEMM3
    }
    if (c == NCH - 1) final_state[lane] = state;  // lane == b*8+d
}

extern "C" void kernel_launch(void* const* d_in, const int* in_sizes, int n_in,
                              void* d_out, int out_size, void* d_ws, size_t ws_size,
                              hipStream_t stream)
{
    (void)in_sizes; (void)n_in; (void)out_size; (void)ws_size;
    const float* x     = (const float*)d_in[0];
    const float* W_in  = (const float*)d_in[1];
    const float* b_in  = (const float*)d_in[2];
    const float* W_g   = (const float*)d_in[3];
    const float* b_g   = (const float*)d_in[4];
    const float* W_out = (const float*)d_in[5];
    const float* b_out = (const float*)d_in[6];

    // workspace layout (identical to the R1-passing version, ~73.4 MB)
    ushort_t* xb     = (ushort_t*)d_ws;                      // 32768*1024 bf16 = 67.1 MB
    ushort_t* comb16 = xb + (size_t)M_TOTAL * E_;            // 32768*32 bf16 = 2.1 MB
    ushort_t* WbigT  = comb16 + (size_t)M_TOTAL * 32;        // 1024*1024 bf16
    ushort_t* Winb   = WbigT + (size_t)E_ * E_;              // 1024*1024 bf16
    ushort_t* WoutTa = Winb + (size_t)E_ * E_;               // 1024*1024 bf16
    ushort_t* WoutT2 = WoutTa + (size_t)E_ * E_;             // 1024*32 bf16
    ushort_t* BT16   = WoutT2 + (size_t)E_ * 32;             // 32*1024 bf16
    float*    Wc     = (float*)(BT16 + (size_t)32 * E_);     // 1024*8 fp32
    float*    bias16 = Wc + 1024 * 8;                        // 32
    float*    bias2v = bias16 + 32;                          // 1024
    float*    chA    = bias2v + E_;                          // 256*64
    float*    chB    = chA + NCH * 64;                       // 256*64

    float* outp = (float*)d_out;
    float* fs = outp + (size_t)M_TOTAL * E_;  // final_state at element 33554432

    // R1-proven prep chain (6 kernels)
    wcomb_kernel<<<E_, 64, 0, stream>>>(W_in, W_g, Wc);
    prep_winb<<<1024, 256, 0, stream>>>(W_in, Winb);
    prep_wouts<<<(E_ * E_) / 256, 256, 0, stream>>>(W_out, WoutTa);
    prep_small<<<256, 256, 0, stream>>>(W_in, Wc, W_out, b_in, W_g, b_g, BT16, WoutT2, bias16);
    bias2_kernel<<<E_ / 64, 64, 0, stream>>>(b_in, W_out, b_out, bias2v);

    // WbigT[1024][1024] = (W_in[:,:1024] @ W_out[:1024,:])^T
    gemm_bt<true, false><<<dim3(E_ / 128, E_ / 128), 256, 0, stream>>>(
        WoutTa, Winb, nullptr, nullptr, WbigT, nullptr, E_, E_, E_, 0, 0, E_);

    // fused cvt+skinny: xb = bf16(x); comb16 = xb @ BT16^T + bias16
    skinny16_cvt<<<M_TOTAL / 64, 256, 0, stream>>>(x, BT16, bias16, xb, comb16);

    // scan
    scan_chunks<<<NCH, 64, 0, stream>>>(comb16, chA, chB);
    scan_apply<<<NCH, 64, 0, stream>>>(comb16, chA, chB, fs);

    // GEMM3': out = xb @ WbigT^T (K=1024) + comb16 @ WoutT2^T (K=32) + bias2
    gemm_bt<false, true><<<dim3(E_ / 128, M_TOTAL / 128), 256, 0, stream>>>(
        xb, WbigT, comb16, WoutT2, outp, bias2v, E_, E_, E_, 32, 32, E_);
}

// Round 6
// 453.474 us; speedup vs baseline: 1.1084x; 1.1084x over previous
//
#include <hip/hip_runtime.h>

typedef unsigned short ushort_t;
typedef __attribute__((ext_vector_type(8))) short short8;
typedef __attribute__((ext_vector_type(4))) float floatx4;

#define B_ 8
#define S_ 4096
#define E_ 1024
#define SD_ 8
#define M_TOTAL (B_ * S_)   /* 32768 rows */
#define NC 1032             /* E+SD real columns of W_in */

__device__ __forceinline__ ushort_t f2bf(float f) {
    union { float f; unsigned u; } v; v.f = f;
    unsigned u = v.u;
    unsigned r = (u + 0x7fffu + ((u >> 16) & 1u)) >> 16;  // RNE
    return (ushort_t)r;
}
__device__ __forceinline__ float bf2f(ushort_t h) {
    union { unsigned u; float f; } v; v.u = ((unsigned)h) << 16;
    return v.f;
}

// Async global->LDS, 16B per lane. LDS dest is wave-uniform base + lane*16.
__device__ __forceinline__ void stage16(ushort_t* lds_base_uniform, const ushort_t* g) {
    __builtin_amdgcn_global_load_lds(
        (const __attribute__((address_space(1))) void*)g,
        (__attribute__((address_space(3))) void*)lds_base_uniform, 16, 0, 0);
}

// ---------------- prepass kernels (R1/R5-proven chain, unchanged) ----------------

// Wc[1024][8] = W_in[1024][1032] @ W_g[1032][8]  (fp32, one wave per row)
__global__ void wcomb_kernel(const float* __restrict__ W_in, const float* __restrict__ Wg,
                             float* __restrict__ Wc) {
    const int k = blockIdx.x;          // row 0..1023
    const int lane = threadIdx.x;      // 64
    float acc[8] = {0.f,0.f,0.f,0.f,0.f,0.f,0.f,0.f};
    for (int c = lane; c < NC; c += 64) {
        float w = W_in[(size_t)k * NC + c];
#pragma unroll
        for (int d = 0; d < 8; d++) acc[d] += w * Wg[(size_t)c * 8 + d];
    }
#pragma unroll
    for (int d = 0; d < 8; d++) {
#pragma unroll
        for (int off = 32; off >= 1; off >>= 1) acc[d] += __shfl_xor(acc[d], off);
    }
    if (lane == 0) {
#pragma unroll
        for (int d = 0; d < 8; d++) Wc[k * 8 + d] = acc[d];
    }
}

// Winb[1024][1024] bf16 = W_in[:, :1024] (coalesced, float4 in / ushort4 out)
__global__ void prep_winb(const float* __restrict__ W, ushort_t* __restrict__ O) {
    int i = blockIdx.x * 256 + threadIdx.x;    // over 1024 * 256
    int k = i >> 8, j0 = (i & 255) * 4;
    float4 v = *(const float4*)(W + (size_t)k * NC + j0);
    ushort4 o;
    o.x = f2bf(v.x); o.y = f2bf(v.y); o.z = f2bf(v.z); o.w = f2bf(v.w);
    *(ushort4*)(O + (size_t)k * E_ + j0) = o;
}

// WoutTa[1024][1024] bf16: WoutTa[n][j] = W_out[j][n]  (j < 1024 only)
__global__ void prep_wouts(const float* __restrict__ W, ushort_t* __restrict__ O) {
    int idx = blockIdx.x * 256 + threadIdx.x;  // 1024*1024
    int n = idx >> 10, j = idx & 1023;
    O[idx] = f2bf(W[(size_t)j * E_ + n]);
}

// BT16[32][1024]: rows 0..7 = W_in[:,1024+n]^T, 8..15 = Wc[:,n-8]^T, 16..31 = 0
// WoutT2[1024][32]: [n][k2] = W_out[1024+k2][n] for k2<8 else 0
// bias16[32]: [0..7]=b_in[1024+d]; [8..15]=b_g[d]+b_in@W_g[:,d]; rest 0
__global__ void prep_small(const float* __restrict__ W_in, const float* __restrict__ Wc,
                           const float* __restrict__ W_out, const float* __restrict__ b_in,
                           const float* __restrict__ Wg, const float* __restrict__ bg,
                           ushort_t* __restrict__ BT16, ushort_t* __restrict__ WoutT2,
                           float* __restrict__ bias16) {
    int idx = blockIdx.x * 256 + threadIdx.x;  // 65536 total
    if (idx < 32768) {
        int n = idx >> 10, k = idx & 1023;
        float v;
        if (n < 8)        v = W_in[(size_t)k * NC + 1024 + n];
        else if (n < 16)  v = Wc[k * 8 + (n - 8)];
        else              v = 0.f;
        BT16[idx] = f2bf(v);
    } else {
        int i2 = idx - 32768;
        int n = i2 >> 5, k2 = i2 & 31;
        float v = (k2 < 8) ? W_out[(size_t)(1024 + k2) * E_ + n] : 0.f;
        WoutT2[i2] = f2bf(v);
    }
    if (idx < 32) {
        float s;
        if (idx < 8) s = b_in[1024 + idx];
        else if (idx < 16) {
            int d = idx - 8;
            s = bg[d];
            for (int j = 0; j < NC; j++) s += b_in[j] * Wg[(size_t)j * 8 + d];
        } else s = 0.f;
        bias16[idx] = s;
    }
}

// bias2[n] = b_out[n] + sum_{j<1024} b_in[j] * W_out[j][n]
__global__ void bias2_kernel(const float* __restrict__ b_in, const float* __restrict__ W_out,
                             const float* __restrict__ b_out, float* __restrict__ bias2) {
    int n = blockIdx.x * 64 + threadIdx.x;     // grid 16 x 64
    float acc = b_out[n];
    for (int j = 0; j < E_; j++) acc += b_in[j] * W_out[(size_t)j * E_ + n];
    bias2[n] = acc;
}

// ---------------- m97-style bf16 MFMA GEMM, B-transposed (R1/R5-proven) ----------------
// C[M][N] = A[M][K] * BT[N][K]^T (+ optional extra 32-wide K-step from A2/BT2) + bias.
template <bool OUT_BF16, bool EXTRA>
__global__ __launch_bounds__(256, 2) void gemm_bt(
    const ushort_t* __restrict__ A, const ushort_t* __restrict__ BT,
    const ushort_t* __restrict__ A2, const ushort_t* __restrict__ BT2,
    void* __restrict__ Cout, const float* __restrict__ bias,
    int K, int lda, int ldb, int lda2, int ldb2, int ldc)
{
    __shared__ __align__(16) ushort_t sA[128 * 32];
    __shared__ __align__(16) ushort_t sB[128 * 32];
    const int tid = threadIdx.x;
    const int wave = tid >> 6;
    const int lane = tid & 63;

    const int gx = gridDim.x;
    int flat = blockIdx.y * gx + blockIdx.x;     // HW dispatch order (x fastest)
    const int band_size = 8 * gx;                // 8 panels per band
    int band = flat / band_size;
    int r = flat - band * band_size;
    const int m0 = (band * 8 + (r & 7)) * 128;   // panel: constant per-XCD within a band
    const int n0 = (r >> 3) * 128;

    const int wm = wave >> 1, wn = wave & 1;   // 2x2 waves -> 64x64 each
    const int fr = lane & 15, fq = lane >> 4;  // fragment row / k-quad
    const int sr = lane >> 2;                  // staging row-in-16
    const int sc = (lane & 3) * 8;             // staging k-chunk (elems)

    floatx4 acc[4][4];
#pragma unroll
    for (int i = 0; i < 4; i++)
#pragma unroll
        for (int j = 0; j < 4; j++) acc[i][j] = (floatx4)0.f;

    const ushort_t* gA = A + (size_t)(m0 + wave * 32 + sr) * lda + sc;
    const ushort_t* gB = BT + (size_t)(n0 + wave * 32 + sr) * ldb + sc;

    for (int k0 = 0; k0 < K; k0 += 32) {
        __syncthreads();
        stage16(&sA[(wave * 32 + 0) * 32], gA + k0);
        stage16(&sA[(wave * 32 + 16) * 32], gA + (size_t)16 * lda + k0);
        stage16(&sB[(wave * 32 + 0) * 32], gB + k0);
        stage16(&sB[(wave * 32 + 16) * 32], gB + (size_t)16 * ldb + k0);
        __syncthreads();  // drains vmcnt(0) for global_load_lds

        short8 a[4], b[4];
#pragma unroll
        for (int i = 0; i < 4; i++)
            a[i] = *(const short8*)&sA[(wm * 64 + i * 16 + fr) * 32 + fq * 8];
#pragma unroll
        for (int j = 0; j < 4; j++)
            b[j] = *(const short8*)&sB[(wn * 64 + j * 16 + fr) * 32 + fq * 8];
#pragma unroll
        for (int i = 0; i < 4; i++)
#pragma unroll
            for (int j = 0; j < 4; j++)
                acc[i][j] = __builtin_amdgcn_mfma_f32_16x16x32_bf16(a[i], b[j], acc[i][j], 0, 0, 0);
    }

    if constexpr (EXTRA) {
        // one more 32-wide K-step from the (A2, BT2) pair (states @ W_out2)
        const ushort_t* gA2 = A2 + (size_t)(m0 + wave * 32 + sr) * lda2 + sc;
        const ushort_t* gB2 = BT2 + (size_t)(n0 + wave * 32 + sr) * ldb2 + sc;
        __syncthreads();
        stage16(&sA[(wave * 32 + 0) * 32], gA2);
        stage16(&sA[(wave * 32 + 16) * 32], gA2 + (size_t)16 * lda2);
        stage16(&sB[(wave * 32 + 0) * 32], gB2);
        stage16(&sB[(wave * 32 + 16) * 32], gB2 + (size_t)16 * ldb2);
        __syncthreads();

        short8 a[4], b[4];
#pragma unroll
        for (int i = 0; i < 4; i++)
            a[i] = *(const short8*)&sA[(wm * 64 + i * 16 + fr) * 32 + fq * 8];
#pragma unroll
        for (int j = 0; j < 4; j++)
            b[j] = *(const short8*)&sB[(wn * 64 + j * 16 + fr) * 32 + fq * 8];
#pragma unroll
        for (int i = 0; i < 4; i++)
#pragma unroll
            for (int j = 0; j < 4; j++)
                acc[i][j] = __builtin_amdgcn_mfma_f32_16x16x32_bf16(a[i], b[j], acc[i][j], 0, 0, 0);
    }

    // epilogue: C/D layout col=lane&15, row=(lane>>4)*4+reg   [m89-verified]
#pragma unroll
    for (int i = 0; i < 4; i++) {
        int row = m0 + wm * 64 + i * 16 + fq * 4;
#pragma unroll
        for (int j = 0; j < 4; j++) {
            int col = n0 + wn * 64 + j * 16 + fr;
            float bv = bias ? bias[col] : 0.f;
#pragma unroll
            for (int r2 = 0; r2 < 4; r2++) {
                float v = acc[i][j][r2] + bv;
                if (OUT_BF16)
                    ((ushort_t*)Cout)[(size_t)(row + r2) * ldc + col] = f2bf(v);
                else
                    ((float*)Cout)[(size_t)(row + r2) * ldc + col] = v;
            }
        }
    }
}

// ---------------- fused cvt + skinny GEMM1, K-split TLP version ----------------
// v2: 2048 blocks (was 512). Each block owns 16 rows; its 4 waves each own a K/4=256
// slice (8-deep MFMA chain, 4x the waves/CU of v1), LDS-reduce the 4 partials.
// Writes xb (bf16 copy of x) as a side effect; comb16 cols 0..7 = state_in,
// 8..15 = gate preact, 16..31 = 0.
__global__ __launch_bounds__(256) void skinny16_cvt(
    const float* __restrict__ X,        // x [32768][1024] fp32
    const ushort_t* __restrict__ BT,    // BT16 [32][1024] (rows 16..31 zero)
    const float* __restrict__ bias,     // [32]
    ushort_t* __restrict__ xb,          // out: bf16 copy of x
    ushort_t* __restrict__ C)           // comb16 [32768][32]
{
    const int tid = threadIdx.x, wave = tid >> 6, lane = tid & 63;
    const int m0 = blockIdx.x * 16;            // 16 rows per block
    const int fr = lane & 15, fq = lane >> 4;
    const int k0w = wave * 256;                // this wave's K-slice

    floatx4 acc = (floatx4)0.f;
    const float*    px  = X  + (size_t)(m0 + fr) * E_ + k0w + fq * 8;
    ushort_t*       pxb = xb + (size_t)(m0 + fr) * E_ + k0w + fq * 8;
    const ushort_t* pb  = BT + (size_t)fr * E_ + k0w + fq * 8;
#pragma unroll
    for (int kk = 0; kk < 256; kk += 32) {
        float4 v0 = *(const float4*)(px + kk);
        float4 v1 = *(const float4*)(px + kk + 4);
        short8 a;
        a[0] = (short)f2bf(v0.x); a[1] = (short)f2bf(v0.y);
        a[2] = (short)f2bf(v0.z); a[3] = (short)f2bf(v0.w);
        a[4] = (short)f2bf(v1.x); a[5] = (short)f2bf(v1.y);
        a[6] = (short)f2bf(v1.z); a[7] = (short)f2bf(v1.w);
        *(short8*)(pxb + kk) = a;              // 16B store
        short8 b0 = *(const short8*)(pb + kk);
        acc = __builtin_amdgcn_mfma_f32_16x16x32_bf16(a, b0, acc, 0, 0, 0);
    }

    // reduce 4 wave-partials: lane (fr,fq) holds partial C[row=fq*4+r][col=fr]
    __shared__ float red[4][16][16];
#pragma unroll
    for (int r = 0; r < 4; r++) red[wave][fq * 4 + r][fr] = acc[r];
    __syncthreads();
    const int row = tid >> 4, col = tid & 15;  // 256 threads = 16x16 outputs
    float v = red[0][row][col] + red[1][row][col] + red[2][row][col] + red[3][row][col]
            + bias[col];
    C[(size_t)(m0 + row) * 32 + col]      = f2bf(v);
    C[(size_t)(m0 + row) * 32 + 16 + col] = (ushort_t)0;   // zero pad cols 16..31
}

// ---------------- fused scan: one kernel, block-parallel (Hillis-Steele) ----------
// 64 blocks: block = b*8+d owns sequence (b,d) of length 4096. 256 threads: thread t
// composes steps [t*16, t*16+16) into (A,B) with f(x)=A*x+B, LDS-scans the 256
// compositions, then applies with the exclusive prefix. state0 = 0.
__global__ __launch_bounds__(256) void scan_fused(
    ushort_t* __restrict__ comb, float* __restrict__ final_state)
{
    const int b = blockIdx.x >> 3, d = blockIdx.x & 7;
    const int t = threadIdx.x;
    __shared__ float sA[256], sB[256];
    const size_t base = (size_t)b * S_ * 32;
    const int s0 = t * 16;

    // pass 1: local composition over 16 steps
    float A = 1.f, Bv = 0.f;
    for (int s = s0; s < s0 + 16; s++) {
        size_t m = base + (size_t)s * 32;
        float z = bf2f(comb[m + 8 + d]);
        float g = 1.f / (1.f + __expf(-z));
        float si = bf2f(comb[m + d]);
        Bv = g * Bv + (1.f - g) * si;
        A *= g;
    }
    sA[t] = A; sB[t] = Bv;
    __syncthreads();

    // inclusive scan of compositions: combine(prev=(a,b_), cur=(rA,rB)) = (a*rA, rA*b_ + rB)
    float rA = A, rB = Bv;
    for (int off = 1; off < 256; off <<= 1) {
        float a = 1.f, b_ = 0.f;
        if (t >= off) { a = sA[t - off]; b_ = sB[t - off]; }
        __syncthreads();
        if (t >= off) {
            float nA = a * rA;
            float nB = rA * b_ + rB;
            rA = nA; rB = nB;
        }
        sA[t] = rA; sB[t] = rB;
        __syncthreads();
    }

    // pass 2: apply with exclusive prefix (inclusive at t-1, applied to state0=0 -> B)
    float state = (t == 0) ? 0.f : sB[t - 1];
    for (int s = s0; s < s0 + 16; s++) {
        size_t m = base + (size_t)s * 32;
        float z = bf2f(comb[m + 8 + d]);
        float g = 1.f / (1.f + __expf(-z));
        float si = bf2f(comb[m + d]);
        state = g * state + (1.f - g) * si;
        comb[m + d] = f2bf(state);    // overwrite si with state for GEMM3
    }
    if (t == 255) final_state[b * 8 + d] = state;
}

extern "C" void kernel_launch(void* const* d_in, const int* in_sizes, int n_in,
                              void* d_out, int out_size, void* d_ws, size_t ws_size,
                              hipStream_t stream)
{
    (void)in_sizes; (void)n_in; (void)out_size; (void)ws_size;
    const float* x     = (const float*)d_in[0];
    const float* W_in  = (const float*)d_in[1];
    const float* b_in  = (const float*)d_in[2];
    const float* W_g   = (const float*)d_in[3];
    const float* b_g   = (const float*)d_in[4];
    const float* W_out = (const float*)d_in[5];
    const float* b_out = (const float*)d_in[6];

    // workspace layout (same as R5, ~73.4 MB)
    ushort_t* xb     = (ushort_t*)d_ws;                      // 32768*1024 bf16 = 67.1 MB
    ushort_t* comb16 = xb + (size_t)M_TOTAL * E_;            // 32768*32 bf16 = 2.1 MB
    ushort_t* WbigT  = comb16 + (size_t)M_TOTAL * 32;        // 1024*1024 bf16
    ushort_t* Winb   = WbigT + (size_t)E_ * E_;              // 1024*1024 bf16
    ushort_t* WoutTa = Winb + (size_t)E_ * E_;               // 1024*1024 bf16
    ushort_t* WoutT2 = WoutTa + (size_t)E_ * E_;             // 1024*32 bf16
    ushort_t* BT16   = WoutT2 + (size_t)E_ * 32;             // 32*1024 bf16
    float*    Wc     = (float*)(BT16 + (size_t)32 * E_);     // 1024*8 fp32
    float*    bias16 = Wc + 1024 * 8;                        // 32
    float*    bias2v = bias16 + 32;                          // 1024

    float* outp = (float*)d_out;
    float* fs = outp + (size_t)M_TOTAL * E_;  // final_state at element 33554432

    // prep chain (R5-proven)
    wcomb_kernel<<<E_, 64, 0, stream>>>(W_in, W_g, Wc);
    prep_winb<<<1024, 256, 0, stream>>>(W_in, Winb);
    prep_wouts<<<(E_ * E_) / 256, 256, 0, stream>>>(W_out, WoutTa);
    prep_small<<<256, 256, 0, stream>>>(W_in, Wc, W_out, b_in, W_g, b_g, BT16, WoutT2, bias16);
    bias2_kernel<<<E_ / 64, 64, 0, stream>>>(b_in, W_out, b_out, bias2v);

    // WbigT[1024][1024] = (W_in[:,:1024] @ W_out[:1024,:])^T
    gemm_bt<true, false><<<dim3(E_ / 128, E_ / 128), 256, 0, stream>>>(
        WoutTa, Winb, nullptr, nullptr, WbigT, nullptr, E_, E_, E_, 0, 0, E_);

    // fused cvt+skinny (K-split TLP): xb = bf16(x); comb16 = xb @ BT16^T + bias16
    skinny16_cvt<<<M_TOTAL / 16, 256, 0, stream>>>(x, BT16, bias16, xb, comb16);

    // fused scan (one launch)
    scan_fused<<<64, 256, 0, stream>>>(comb16, fs);

    // GEMM3': out = xb @ WbigT^T (K=1024) + comb16 @ WoutT2^T (K=32) + bias2
    gemm_bt<false, true><<<dim3(E_ / 128, M_TOTAL / 128), 256, 0, stream>>>(
        xb, WbigT, comb16, WoutT2, outp, bias2v, E_, E_, E_, 32, 32, E_);
}

// Round 8
// 451.005 us; speedup vs baseline: 1.1145x; 1.0055x over previous
//
#include <hip/hip_runtime.h>

typedef unsigned short ushort_t;
typedef __attribute__((ext_vector_type(8))) short short8;
typedef __attribute__((ext_vector_type(4))) float floatx4;

#define B_ 8
#define S_ 4096
#define E_ 1024
#define SD_ 8
#define M_TOTAL (B_ * S_)   /* 32768 rows */
#define NC 1032             /* E+SD real columns of W_in */

__device__ __forceinline__ ushort_t f2bf(float f) {
    union { float f; unsigned u; } v; v.f = f;
    unsigned u = v.u;
    unsigned r = (u + 0x7fffu + ((u >> 16) & 1u)) >> 16;  // RNE
    return (ushort_t)r;
}
__device__ __forceinline__ float bf2f(ushort_t h) {
    union { unsigned u; float f; } v; v.u = ((unsigned)h) << 16;
    return v.f;
}

// Async global->LDS, 16B per lane. LDS dest is wave-uniform base + lane*16.
__device__ __forceinline__ void stage16(ushort_t* lds_base_uniform, const ushort_t* g) {
    __builtin_amdgcn_global_load_lds(
        (const __attribute__((address_space(1))) void*)g,
        (__attribute__((address_space(3))) void*)lds_base_uniform, 16, 0, 0);
}

// ---------------- prep_ew2: PROBE — prep_winb + prep_wouts merged, bodies verbatim --
// blocks [0,1024):    Winb = bf16(W_in[:, :1024])       (exact prep_winb body)
// blocks [1024,5120): WoutTa[n][j] = bf16(W_out[j][n])  (exact prep_wouts body)
__global__ __launch_bounds__(256) void prep_ew2(
    const float* __restrict__ W_in, const float* __restrict__ W_out,
    ushort_t* __restrict__ Winb, ushort_t* __restrict__ WoutTa)
{
    const int bid = blockIdx.x, tid = threadIdx.x;
    if (bid < 1024) {
        int i = bid * 256 + tid;                 // over 1024 * 256
        int k = i >> 8, j0 = (i & 255) * 4;
        float4 v = *(const float4*)(W_in + (size_t)k * NC + j0);
        ushort4 o;
        o.x = f2bf(v.x); o.y = f2bf(v.y); o.z = f2bf(v.z); o.w = f2bf(v.w);
        *(ushort4*)(Winb + (size_t)k * E_ + j0) = o;
    } else {
        int idx = (bid - 1024) * 256 + tid;      // 1024*1024
        int n = idx >> 10, j = idx & 1023;
        WoutTa[idx] = f2bf(W_out[(size_t)j * E_ + n]);
    }
}

// ---------------- remaining prep (R6-proven chain, byte-identical) ----------------

// Wc[1024][8] = W_in[1024][1032] @ W_g[1032][8]  (fp32, one wave per row)
__global__ void wcomb_kernel(const float* __restrict__ W_in, const float* __restrict__ Wg,
                             float* __restrict__ Wc) {
    const int k = blockIdx.x;          // row 0..1023
    const int lane = threadIdx.x;      // 64
    float acc[8] = {0.f,0.f,0.f,0.f,0.f,0.f,0.f,0.f};
    for (int c = lane; c < NC; c += 64) {
        float w = W_in[(size_t)k * NC + c];
#pragma unroll
        for (int d = 0; d < 8; d++) acc[d] += w * Wg[(size_t)c * 8 + d];
    }
#pragma unroll
    for (int d = 0; d < 8; d++) {
#pragma unroll
        for (int off = 32; off >= 1; off >>= 1) acc[d] += __shfl_xor(acc[d], off);
    }
    if (lane == 0) {
#pragma unroll
        for (int d = 0; d < 8; d++) Wc[k * 8 + d] = acc[d];
    }
}

// BT16[32][1024]: rows 0..7 = W_in[:,1024+n]^T, 8..15 = Wc[:,n-8]^T, 16..31 = 0
// WoutT2[1024][32]: [n][k2] = W_out[1024+k2][n] for k2<8 else 0
// bias16[32]: [0..7]=b_in[1024+d]; [8..15]=b_g[d]+b_in@W_g[:,d]; rest 0
__global__ void prep_small(const float* __restrict__ W_in, const float* __restrict__ Wc,
                           const float* __restrict__ W_out, const float* __restrict__ b_in,
                           const float* __restrict__ Wg, const float* __restrict__ bg,
                           ushort_t* __restrict__ BT16, ushort_t* __restrict__ WoutT2,
                           float* __restrict__ bias16) {
    int idx = blockIdx.x * 256 + threadIdx.x;  // 65536 total
    if (idx < 32768) {
        int n = idx >> 10, k = idx & 1023;
        float v;
        if (n < 8)        v = W_in[(size_t)k * NC + 1024 + n];
        else if (n < 16)  v = Wc[k * 8 + (n - 8)];
        else              v = 0.f;
        BT16[idx] = f2bf(v);
    } else {
        int i2 = idx - 32768;
        int n = i2 >> 5, k2 = i2 & 31;
        float v = (k2 < 8) ? W_out[(size_t)(1024 + k2) * E_ + n] : 0.f;
        WoutT2[i2] = f2bf(v);
    }
    if (idx < 32) {
        float s;
        if (idx < 8) s = b_in[1024 + idx];
        else if (idx < 16) {
            int d = idx - 8;
            s = bg[d];
            for (int j = 0; j < NC; j++) s += b_in[j] * Wg[(size_t)j * 8 + d];
        } else s = 0.f;
        bias16[idx] = s;
    }
}

// bias2[n] = b_out[n] + sum_{j<1024} b_in[j] * W_out[j][n]
__global__ void bias2_kernel(const float* __restrict__ b_in, const float* __restrict__ W_out,
                             const float* __restrict__ b_out, float* __restrict__ bias2) {
    int n = blockIdx.x * 64 + threadIdx.x;     // grid 16 x 64
    float acc = b_out[n];
    for (int j = 0; j < E_; j++) acc += b_in[j] * W_out[(size_t)j * E_ + n];
    bias2[n] = acc;
}

// ---------------- m97-style bf16 MFMA GEMM, B-transposed (R5/R6-proven) ----------------
// C[M][N] = A[M][K] * BT[N][K]^T (+ optional extra 32-wide K-step from A2/BT2) + bias.
template <bool OUT_BF16, bool EXTRA>
__global__ __launch_bounds__(256, 2) void gemm_bt(
    const ushort_t* __restrict__ A, const ushort_t* __restrict__ BT,
    const ushort_t* __restrict__ A2, const ushort_t* __restrict__ BT2,
    void* __restrict__ Cout, const float* __restrict__ bias,
    int K, int lda, int ldb, int lda2, int ldb2, int ldc)
{
    __shared__ __align__(16) ushort_t sA[128 * 32];
    __shared__ __align__(16) ushort_t sB[128 * 32];
    const int tid = threadIdx.x;
    const int wave = tid >> 6;
    const int lane = tid & 63;

    const int gx = gridDim.x;
    int flat = blockIdx.y * gx + blockIdx.x;     // HW dispatch order (x fastest)
    const int band_size = 8 * gx;                // 8 panels per band
    int band = flat / band_size;
    int r = flat - band * band_size;
    const int m0 = (band * 8 + (r & 7)) * 128;   // panel: constant per-XCD within a band
    const int n0 = (r >> 3) * 128;

    const int wm = wave >> 1, wn = wave & 1;   // 2x2 waves -> 64x64 each
    const int fr = lane & 15, fq = lane >> 4;  // fragment row / k-quad
    const int sr = lane >> 2;                  // staging row-in-16
    const int sc = (lane & 3) * 8;             // staging k-chunk (elems)

    floatx4 acc[4][4];
#pragma unroll
    for (int i = 0; i < 4; i++)
#pragma unroll
        for (int j = 0; j < 4; j++) acc[i][j] = (floatx4)0.f;

    const ushort_t* gA = A + (size_t)(m0 + wave * 32 + sr) * lda + sc;
    const ushort_t* gB = BT + (size_t)(n0 + wave * 32 + sr) * ldb + sc;

    for (int k0 = 0; k0 < K; k0 += 32) {
        __syncthreads();
        stage16(&sA[(wave * 32 + 0) * 32], gA + k0);
        stage16(&sA[(wave * 32 + 16) * 32], gA + (size_t)16 * lda + k0);
        stage16(&sB[(wave * 32 + 0) * 32], gB + k0);
        stage16(&sB[(wave * 32 + 16) * 32], gB + (size_t)16 * ldb + k0);
        __syncthreads();  // drains vmcnt(0) for global_load_lds

        short8 a[4], b[4];
#pragma unroll
        for (int i = 0; i < 4; i++)
            a[i] = *(const short8*)&sA[(wm * 64 + i * 16 + fr) * 32 + fq * 8];
#pragma unroll
        for (int j = 0; j < 4; j++)
            b[j] = *(const short8*)&sB[(wn * 64 + j * 16 + fr) * 32 + fq * 8];
#pragma unroll
        for (int i = 0; i < 4; i++)
#pragma unroll
            for (int j = 0; j < 4; j++)
                acc[i][j] = __builtin_amdgcn_mfma_f32_16x16x32_bf16(a[i], b[j], acc[i][j], 0, 0, 0);
    }

    if constexpr (EXTRA) {
        // one more 32-wide K-step from the (A2, BT2) pair (states @ W_out2)
        const ushort_t* gA2 = A2 + (size_t)(m0 + wave * 32 + sr) * lda2 + sc;
        const ushort_t* gB2 = BT2 + (size_t)(n0 + wave * 32 + sr) * ldb2 + sc;
        __syncthreads();
        stage16(&sA[(wave * 32 + 0) * 32], gA2);
        stage16(&sA[(wave * 32 + 16) * 32], gA2 + (size_t)16 * lda2);
        stage16(&sB[(wave * 32 + 0) * 32], gB2);
        stage16(&sB[(wave * 32 + 16) * 32], gB2 + (size_t)16 * ldb2);
        __syncthreads();

        short8 a[4], b[4];
#pragma unroll
        for (int i = 0; i < 4; i++)
            a[i] = *(const short8*)&sA[(wm * 64 + i * 16 + fr) * 32 + fq * 8];
#pragma unroll
        for (int j = 0; j < 4; j++)
            b[j] = *(const short8*)&sB[(wn * 64 + j * 16 + fr) * 32 + fq * 8];
#pragma unroll
        for (int i = 0; i < 4; i++)
#pragma unroll
            for (int j = 0; j < 4; j++)
                acc[i][j] = __builtin_amdgcn_mfma_f32_16x16x32_bf16(a[i], b[j], acc[i][j], 0, 0, 0);
    }

    // epilogue: C/D layout col=lane&15, row=(lane>>4)*4+reg   [m89-verified]
#pragma unroll
    for (int i = 0; i < 4; i++) {
        int row = m0 + wm * 64 + i * 16 + fq * 4;
#pragma unroll
        for (int j = 0; j < 4; j++) {
            int col = n0 + wn * 64 + j * 16 + fr;
            float bv = bias ? bias[col] : 0.f;
#pragma unroll
            for (int r2 = 0; r2 < 4; r2++) {
                float v = acc[i][j][r2] + bv;
                if (OUT_BF16)
                    ((ushort_t*)Cout)[(size_t)(row + r2) * ldc + col] = f2bf(v);
                else
                    ((float*)Cout)[(size_t)(row + r2) * ldc + col] = v;
            }
        }
    }
}

// ---------------- fused cvt + skinny GEMM1, K-split TLP (R6-proven) ----------------
// 2048 blocks; block owns 16 rows; 4 waves each own a K/4=256 slice, LDS-reduce.
__global__ __launch_bounds__(256) void skinny16_cvt(
    const float* __restrict__ X,        // x [32768][1024] fp32
    const ushort_t* __restrict__ BT,    // BT16 [32][1024] (rows 16..31 zero)
    const float* __restrict__ bias,     // [32]
    ushort_t* __restrict__ xb,          // out: bf16 copy of x
    ushort_t* __restrict__ C)           // comb16 [32768][32]
{
    const int tid = threadIdx.x, wave = tid >> 6, lane = tid & 63;
    const int m0 = blockIdx.x * 16;            // 16 rows per block
    const int fr = lane & 15, fq = lane >> 4;
    const int k0w = wave * 256;                // this wave's K-slice

    floatx4 acc = (floatx4)0.f;
    const float*    px  = X  + (size_t)(m0 + fr) * E_ + k0w + fq * 8;
    ushort_t*       pxb = xb + (size_t)(m0 + fr) * E_ + k0w + fq * 8;
    const ushort_t* pb  = BT + (size_t)fr * E_ + k0w + fq * 8;
#pragma unroll
    for (int kk = 0; kk < 256; kk += 32) {
        float4 v0 = *(const float4*)(px + kk);
        float4 v1 = *(const float4*)(px + kk + 4);
        short8 a;
        a[0] = (short)f2bf(v0.x); a[1] = (short)f2bf(v0.y);
        a[2] = (short)f2bf(v0.z); a[3] = (short)f2bf(v0.w);
        a[4] = (short)f2bf(v1.x); a[5] = (short)f2bf(v1.y);
        a[6] = (short)f2bf(v1.z); a[7] = (short)f2bf(v1.w);
        *(short8*)(pxb + kk) = a;              // 16B store
        short8 b0 = *(const short8*)(pb + kk);
        acc = __builtin_amdgcn_mfma_f32_16x16x32_bf16(a, b0, acc, 0, 0, 0);
    }

    // reduce 4 wave-partials: lane (fr,fq) holds partial C[row=fq*4+r][col=fr]
    __shared__ float red[4][16][16];
#pragma unroll
    for (int r = 0; r < 4; r++) red[wave][fq * 4 + r][fr] = acc[r];
    __syncthreads();
    const int row = tid >> 4, col = tid & 15;  // 256 threads = 16x16 outputs
    float v = red[0][row][col] + red[1][row][col] + red[2][row][col] + red[3][row][col]
            + bias[col];
    C[(size_t)(m0 + row) * 32 + col]      = f2bf(v);
    C[(size_t)(m0 + row) * 32 + 16 + col] = (ushort_t)0;   // zero pad cols 16..31
}

// ---------------- fused scan (R6-proven): one kernel, Hillis-Steele ----------------
__global__ __launch_bounds__(256) void scan_fused(
    ushort_t* __restrict__ comb, float* __restrict__ final_state)
{
    const int b = blockIdx.x >> 3, d = blockIdx.x & 7;
    const int t = threadIdx.x;
    __shared__ float sA[256], sB[256];
    const size_t base = (size_t)b * S_ * 32;
    const int s0 = t * 16;

    // pass 1: local composition over 16 steps
    float A = 1.f, Bv = 0.f;
    for (int s = s0; s < s0 + 16; s++) {
        size_t m = base + (size_t)s * 32;
        float z = bf2f(comb[m + 8 + d]);
        float g = 1.f / (1.f + __expf(-z));
        float si = bf2f(comb[m + d]);
        Bv = g * Bv + (1.f - g) * si;
        A *= g;
    }
    sA[t] = A; sB[t] = Bv;
    __syncthreads();

    // inclusive scan of compositions
    float rA = A, rB = Bv;
    for (int off = 1; off < 256; off <<= 1) {
        float a = 1.f, b_ = 0.f;
        if (t >= off) { a = sA[t - off]; b_ = sB[t - off]; }
        __syncthreads();
        if (t >= off) {
            float nA = a * rA;
            float nB = rA * b_ + rB;
            rA = nA; rB = nB;
        }
        sA[t] = rA; sB[t] = rB;
        __syncthreads();
    }

    // pass 2: apply with exclusive prefix
    float state = (t == 0) ? 0.f : sB[t - 1];
    for (int s = s0; s < s0 + 16; s++) {
        size_t m = base + (size_t)s * 32;
        float z = bf2f(comb[m + 8 + d]);
        float g = 1.f / (1.f + __expf(-z));
        float si = bf2f(comb[m + d]);
        state = g * state + (1.f - g) * si;
        comb[m + d] = f2bf(state);    // overwrite si with state for GEMM3
    }
    if (t == 255) final_state[b * 8 + d] = state;
}

extern "C" void kernel_launch(void* const* d_in, const int* in_sizes, int n_in,
                              void* d_out, int out_size, void* d_ws, size_t ws_size,
                              hipStream_t stream)
{
    (void)in_sizes; (void)n_in; (void)out_size; (void)ws_size;
    const float* x     = (const float*)d_in[0];
    const float* W_in  = (const float*)d_in[1];
    const float* b_in  = (const float*)d_in[2];
    const float* W_g   = (const float*)d_in[3];
    const float* b_g   = (const float*)d_in[4];
    const float* W_out = (const float*)d_in[5];
    const float* b_out = (const float*)d_in[6];

    // workspace layout (identical to R6, ~73.4 MB)
    ushort_t* xb     = (ushort_t*)d_ws;                      // 32768*1024 bf16 = 67.1 MB
    ushort_t* comb16 = xb + (size_t)M_TOTAL * E_;            // 32768*32 bf16 = 2.1 MB
    ushort_t* WbigT  = comb16 + (size_t)M_TOTAL * 32;        // 1024*1024 bf16
    ushort_t* Winb   = WbigT + (size_t)E_ * E_;              // 1024*1024 bf16
    ushort_t* WoutTa = Winb + (size_t)E_ * E_;               // 1024*1024 bf16
    ushort_t* WoutT2 = WoutTa + (size_t)E_ * E_;             // 1024*32 bf16
    ushort_t* BT16   = WoutT2 + (size_t)E_ * 32;             // 32*1024 bf16
    float*    Wc     = (float*)(BT16 + (size_t)32 * E_);     // 1024*8 fp32
    float*    bias16 = Wc + 1024 * 8;                        // 32
    float*    bias2v = bias16 + 32;                          // 1024

    float* outp = (float*)d_out;
    float* fs = outp + (size_t)M_TOTAL * E_;  // final_state at element 33554432

    // 1) PROBE: merged elementwise prep (replaces prep_winb + prep_wouts)
    prep_ew2<<<5120, 256, 0, stream>>>(W_in, W_out, Winb, WoutTa);
    // 2-4) rest of the R6-proven prep chain
    wcomb_kernel<<<E_, 64, 0, stream>>>(W_in, W_g, Wc);
    prep_small<<<256, 256, 0, stream>>>(W_in, Wc, W_out, b_in, W_g, b_g, BT16, WoutT2, bias16);
    bias2_kernel<<<E_ / 64, 64, 0, stream>>>(b_in, W_out, b_out, bias2v);

    // 5) WbigT[1024][1024] = (W_in[:,:1024] @ W_out[:1024,:])^T
    gemm_bt<true, false><<<dim3(E_ / 128, E_ / 128), 256, 0, stream>>>(
        WoutTa, Winb, nullptr, nullptr, WbigT, nullptr, E_, E_, E_, 0, 0, E_);

    // 6) fused cvt+skinny: xb = bf16(x); comb16 = xb @ BT16^T + bias16
    skinny16_cvt<<<M_TOTAL / 16, 256, 0, stream>>>(x, BT16, bias16, xb, comb16);

    // 7) fused scan
    scan_fused<<<64, 256, 0, stream>>>(comb16, fs);

    // 8) GEMM3': out = xb @ WbigT^T (K=1024) + comb16 @ WoutT2^T (K=32) + bias2
    gemm_bt<false, true><<<dim3(E_ / 128, M_TOTAL / 128), 256, 0, stream>>>(
        xb, WbigT, comb16, WoutT2, outp, bias2v, E_, E_, E_, 32, 32, E_);
}